// Round 16
// baseline (121.535 us; speedup 1.0000x reference)
//
#include <hip/hip_runtime.h>

// RetNet retention: B=4, S=4096, D=2048, H=256, gamma=1.05.
// R16 (gemm only): BK 64->128 with FULL double-buffering of A and B.
// R13-15 refuted prefetch-depth/compiler-pinning/occupancy/LDS-traffic as
// the gemm's residual; last unfalsified: barrier frequency (4 BAR + gates
// per 64-K = 128 BAR/block). BK=128 + full dbuf has zero intra-iter
// cross-wave hazards -> 1 BAR + 1 vmcnt(0) per 128-K = 16 BAR/block.
// LDS 163840B (160KiB max; AITER precedent). BM=128 BN=192, 512thr 2x4,
// acc[4][3]=48 AGPR, ~110 VGPR at 2 waves/SIMD. Grid 512 = 2 passes/CU.

typedef unsigned short u16;
typedef __attribute__((ext_vector_type(8))) short bf16x8;
typedef __attribute__((ext_vector_type(4))) float f32x4;

#define S_LEN 4096
#define DMODEL 2048
#define HSZ 256
#define NQKV 768
#define WINDOW 128
#define NT2 16             // K tiles of 128 (2048/128)

__device__ __forceinline__ u16 f2bf(float f) {
  union { float f; unsigned u; } v; v.f = f;
  unsigned r = v.u + 0x7FFFu + ((v.u >> 16) & 1u);   // RNE
  return (u16)(r >> 16);
}

__device__ __forceinline__ void glds16(const void* g, void* l) {
  __builtin_amdgcn_global_load_lds(
      (const __attribute__((address_space(1))) unsigned int*)g,
      (__attribute__((address_space(3))) unsigned int*)l, 16, 0, 0);
}

#define BAR() __builtin_amdgcn_s_barrier()
#define VM0() do { asm volatile("s_waitcnt vmcnt(0)" ::: "memory"); \
                   __builtin_amdgcn_sched_barrier(0); } while (0)

// ---------------- 1) X fp32 -> bf16 ----------------
__global__ __launch_bounds__(256) void k_convertX(const float* __restrict__ X,
                                                  u16* __restrict__ Xb) {
  int t = blockIdx.x * 256 + threadIdx.x;
  const float4* src = (const float4*)X;
  float4 a = src[t * 2], b = src[t * 2 + 1];
  uint4 o;
  o.x = f2bf(a.x) | ((unsigned)f2bf(a.y) << 16);
  o.y = f2bf(a.z) | ((unsigned)f2bf(a.w) << 16);
  o.z = f2bf(b.x) | ((unsigned)f2bf(b.y) << 16);
  o.w = f2bf(b.z) | ((unsigned)f2bf(b.w) << 16);
  ((uint4*)Xb)[t] = o;
}

// ---------------- 2) W -> WcatT [768][2048] bf16 ----------------
__global__ __launch_bounds__(256) void k_transposeW(const float* __restrict__ Wq,
                                                    const float* __restrict__ Wk,
                                                    const float* __restrict__ Wv,
                                                    u16* __restrict__ Wt) {
  __shared__ float s[32][33];
  int bid = blockIdx.x;
  int nt = bid % 24, kt = bid / 24;
  int n0 = nt * 32, k0 = kt * 32;
  const float* W = (n0 < 256) ? Wq : (n0 < 512 ? Wk : Wv);
  int nc = n0 & 255;
  int tx = threadIdx.x & 31, ty = threadIdx.x >> 5;
#pragma unroll
  for (int j = 0; j < 4; j++)
    s[ty + j * 8][tx] = W[(k0 + ty + j * 8) * HSZ + nc + tx];
  __syncthreads();
#pragma unroll
  for (int j = 0; j < 4; j++) {
    int nl = ty + j * 8;
    Wt[(n0 + nl) * DMODEL + k0 + tx] = f2bf(s[tx][nl]);
  }
}

// ---------------- 3) QKV GEMM: 128x192, BK=128, full dbuf ------------------
// LDS rows are 256B (128 bf16). Physical granule gl of row r holds source
// granule gl ^ (r & 15); readers XOR the same key.
__device__ __forceinline__ bf16x8 ldf2(const char* base, int r, int gr) {
  return *(const bf16x8*)(base + r * 256 + (((gr) ^ (r & 15)) << 4));
}
// A tile 128x128 bf16 = 32KB, 4 glds16/thread (512 threads)
__device__ __forceinline__ void stageA(const u16* Asrc, char* base, int t,
                                       int tid) {
#pragma unroll
  for (int j = 0; j < 4; j++) {
    int sr = j * 32 + (tid >> 4);
    int gs = (tid & 15) ^ (sr & 15);
    glds16(Asrc + (size_t)sr * DMODEL + t * 128 + gs * 8,
           base + j * 8192 + tid * 16);
  }
}
// B chunk cb (64 of 192 rows) = 16KB, 2 glds16/thread
__device__ __forceinline__ void stageB(const u16* Bsrc, char* bbase, int t,
                                       int cb, int tid) {
#pragma unroll
  for (int i = 0; i < 2; i++) {
    int srl = i * 32 + (tid >> 4);
    int row = cb * 64 + srl;
    int gs = (tid & 15) ^ (row & 15);
    glds16(Bsrc + (size_t)row * DMODEL + t * 128 + gs * 8,
           bbase + cb * 16384 + i * 8192 + tid * 16);
  }
}
__device__ __forceinline__ void read_a(const char* Ac, int wm, int c, int g,
                                       bf16x8 (&af)[4][4]) {
#pragma unroll
  for (int m = 0; m < 4; m++) {
    int r = wm * 64 + m * 16 + c;
#pragma unroll
    for (int kc = 0; kc < 4; kc++) af[m][kc] = ldf2(Ac, r, kc * 4 + g);
  }
}
__device__ __forceinline__ void read_bg(const char* Bc, int wn, int fn,
                                        int c, int g, bf16x8 (&bf)[4]) {
  int r = wn * 48 + fn * 16 + c;
#pragma unroll
  for (int kc = 0; kc < 4; kc++) bf[kc] = ldf2(Bc, r, kc * 4 + g);
}
__device__ __forceinline__ void mfma_g(const bf16x8 (&af)[4][4], const bf16x8 (&bf)[4],
                                       f32x4 (&acc)[4][3], int fn) {
  __builtin_amdgcn_s_setprio(1);
#pragma unroll
  for (int m = 0; m < 4; m++)
#pragma unroll
    for (int kc = 0; kc < 4; kc++)
      acc[m][fn] = __builtin_amdgcn_mfma_f32_16x16x32_bf16(
          af[m][kc], bf[kc], acc[m][fn], 0, 0, 0);
  __builtin_amdgcn_s_setprio(0);
}

__global__ __launch_bounds__(512, 1) void k_gemm(const u16* __restrict__ Xb,
                                                 const u16* __restrict__ Wt,
                                                 u16* __restrict__ QKV) {
  __shared__ __attribute__((aligned(16))) char lds[163840]; // A 2x32K + B 2x48K
  int tid = threadIdx.x;
  int w = tid >> 6, l = tid & 63, g = l >> 4, c = l & 15;
  int wm = w >> 2, wn = w & 3;          // 2 x 4 wave grid
  int swz = (blockIdx.x & 7) * 64 + (blockIdx.x >> 3);  // bijective (512%8==0)
  int bm = swz & 127, bn = swz >> 7;
  size_t m0 = (size_t)bm * 128, n0 = (size_t)bn * 192;
  const u16* Asrc = Xb + m0 * DMODEL;
  const u16* Bsrc = Wt + n0 * DMODEL;
#define ABUF(b) (lds + (b) * 32768)
#define BBUF(b) (lds + 65536 + (b) * 49152)

  f32x4 acc[4][3];
#pragma unroll
  for (int i = 0; i < 4; i++)
#pragma unroll
    for (int j = 0; j < 3; j++) acc[i][j] = (f32x4){0.f, 0.f, 0.f, 0.f};

  // prologue: tiles 0 and 1 fully staged; drain all.
  stageA(Asrc, ABUF(0), 0, tid);
  stageB(Bsrc, BBUF(0), 0, 0, tid);
  stageB(Bsrc, BBUF(0), 0, 1, tid);
  stageB(Bsrc, BBUF(0), 0, 2, tid);
  stageA(Asrc, ABUF(1), 1, tid);
  stageB(Bsrc, BBUF(1), 1, 0, tid);
  stageB(Bsrc, BBUF(1), 1, 1, tid);
  stageB(Bsrc, BBUF(1), 1, 2, tid);
  VM0();
  BAR();

  bf16x8 af[4][4], bf[4];
  for (int u = 0; u < NT2; u++) {
    bool pre = (u + 1 < NT2);
    const char* Ac = ABUF(u & 1);
    const char* Bc = BBUF(u & 1);
    char* An = ABUF((u + 1) & 1);
    char* Bn = BBUF((u + 1) & 1);
    // ---- P1: read A + B fn0; stage B(u+1) c0,c1; MFMA fn0 ----
    read_a(Ac, wm, c, g, af);
    read_bg(Bc, wn, 0, c, g, bf);
    if (pre) { stageB(Bsrc, Bn, u + 1, 0, tid);
               stageB(Bsrc, Bn, u + 1, 1, tid); }
    mfma_g(af, bf, acc, 0);
    // ---- P2: read B fn1; stage B(u+1) c2 + A(u+1); MFMA fn1 ----
    read_bg(Bc, wn, 1, c, g, bf);
    if (pre) { stageB(Bsrc, Bn, u + 1, 2, tid);
               stageA(Asrc, An, u + 1, tid); }
    mfma_g(af, bf, acc, 1);
    // ---- P3: read B fn2; MFMA fn2; drain; publish ----
    read_bg(Bc, wn, 2, c, g, bf);
    mfma_g(af, bf, acc, 2);
    VM0();
    BAR();
  }

#pragma unroll
  for (int fm = 0; fm < 4; fm++)
#pragma unroll
    for (int fn = 0; fn < 3; fn++)
#pragma unroll
      for (int r = 0; r < 4; r++) {
        size_t row = m0 + wm * 64 + fm * 16 + g * 4 + r;
        size_t col = n0 + wn * 48 + fn * 16 + c;
        QKV[row * NQKV + col] = f2bf(acc[fm][fn][r]);
      }
}

// ---------------- 4) Vt[b][h][s] = V[b][s][h] ------------------------------
__global__ __launch_bounds__(256) void k_transposeV(const u16* __restrict__ QKV,
                                                    u16* __restrict__ Vt) {
  __shared__ __attribute__((aligned(16))) u16 s[64 * 72];
  int bid = blockIdx.x;
  int ht = bid & 3, st = (bid >> 2) & 63, b = bid >> 8;
  int s0 = st * 64, h0 = ht * 64;
  int tid = threadIdx.x;
#pragma unroll
  for (int i = 0; i < 2; i++) {
    int gr = i * 256 + tid;
    int rs = gr >> 3, cg = gr & 7;
    uint4 v = *(const uint4*)(QKV + (size_t)(b * S_LEN + s0 + rs) * NQKV + 512 + h0 + cg * 8);
    *(uint4*)(s + rs * 72 + cg * 8) = v;
  }
  __syncthreads();
#pragma unroll
  for (int i = 0; i < 2; i++) {
    int gr = i * 256 + tid;
    int hr = gr >> 3, cg = gr & 7;
    u16 u[8];
#pragma unroll
    for (int j = 0; j < 8; j++) u[j] = s[(cg * 8 + j) * 72 + hr];
    uint4 o;
    o.x = u[0] | ((unsigned)u[1] << 16);
    o.y = u[2] | ((unsigned)u[3] << 16);
    o.z = u[4] | ((unsigned)u[5] << 16);
    o.w = u[6] | ((unsigned)u[7] << 16);
    *(uint4*)(Vt + (size_t)b * (HSZ * S_LEN) + (size_t)(h0 + hr) * S_LEN + s0 + cg * 8) = o;
  }
}

// ---------------- 5) banded retention, 8-wave parity split -----------------
__device__ __forceinline__ void attn_stage(const u16* __restrict__ QKV,
                                           const u16* __restrict__ Vt,
                                           int b, int t0, char* sK, char* sV, int tg) {
#pragma unroll
  for (int i = 0; i < 8; i++) {
    int gr = i * 256 + tg;
    {
      int row = gr >> 5, cg = gr & 31;
      uint4 v = *(const uint4*)(QKV + (size_t)(b * S_LEN + t0 + row) * NQKV + 256 + cg * 8);
      *(uint4*)(sK + ((row * 512 + cg * 16) ^ ((row & 7) << 4))) = v;
    }
    {
      int h = gr >> 3, cg = gr & 7;
      uint4 v = *(const uint4*)(Vt + (size_t)b * (HSZ * S_LEN) + (size_t)h * S_LEN + t0 + cg * 8);
      *(uint4*)(sV + ((h * 128 + cg * 16) ^ ((h & 7) << 4))) = v;
    }
  }
}

__device__ __forceinline__ void attn_compute(const char* sK, const char* sV,
                                             u16* sPw, const bf16x8 (&qf)[8],
                                             f32x4 (&acc)[16], int s0, int t0,
                                             int wq, int g, int c, float cl,
                                             const float (&bk)[4]) {
  f32x4 z = {0.f, 0.f, 0.f, 0.f};
  f32x4 sc[4];
  sc[0] = z; sc[1] = z; sc[2] = z; sc[3] = z;
#pragma unroll
  for (int f = 0; f < 4; f++) {
    int row = f * 16 + c;
    int rb = row * 512, sw = (row & 7) << 4;
#pragma unroll
    for (int kc = 0; kc < 8; kc++) {
      bf16x8 kf = *(const bf16x8*)(sK + ((rb + kc * 64 + g * 16) ^ sw));
      sc[f] = __builtin_amdgcn_mfma_f32_16x16x32_bf16(qf[kc], kf, sc[f], 0, 0, 0);
    }
  }
  int qb = s0 + wq * 16 + g * 4;
  int dt = qb - t0;
  float ar[4];
#pragma unroll
  for (int r = 0; r < 4; r++) ar[r] = __expf(cl * (float)(dt + r)) * 0.0625f;
#pragma unroll
  for (int f = 0; f < 4; f++) {
#pragma unroll
    for (int r = 0; r < 4; r++) {
      float p = sc[f][r] * ar[r] * bk[f];
      p = (dt + r - f * 16 - c >= 0) ? p : 0.f;
      sPw[(g * 4 + r) * 72 + f * 16 + c] = f2bf(p);
    }
  }
  bf16x8 pa[2];
#pragma unroll
  for (int kc = 0; kc < 2; kc++)
    pa[kc] = *(const bf16x8*)(sPw + c * 72 + kc * 32 + g * 8);
#pragma unroll
  for (int of = 0; of < 16; of++) {
#pragma unroll
    for (int kc = 0; kc < 2; kc++) {
      int hr = of * 16 + c;
      bf16x8 vf = *(const bf16x8*)(sV + ((hr * 128 + kc * 64 + g * 16) ^ ((hr & 7) << 4)));
      acc[of] = __builtin_amdgcn_mfma_f32_16x16x32_bf16(pa[kc], vf, acc[of], 0, 0, 0);
    }
  }
}

__global__ __launch_bounds__(512, 2) void k_attn(const u16* __restrict__ QKV,
                                                 const u16* __restrict__ Vt,
                                                 const float* __restrict__ decay,
                                                 float* __restrict__ out) {
  __shared__ __attribute__((aligned(16))) char smem[140288];
  int logical = (blockIdx.x & 7) * 32 + (blockIdx.x >> 3);
  int b = logical >> 6, qt = logical & 63, s0 = qt * 64;
  int tid = threadIdx.x, wid = tid >> 6, l = tid & 63, g = l >> 4, c = l & 15;
  int gid = wid >> 2, wq = wid & 3, tg = tid & 255;
  float cl = -decay[0];

  bf16x8 qf[8];
  const u16* qrow = QKV + (size_t)(b * S_LEN + s0 + wq * 16 + c) * NQKV;
#pragma unroll
  for (int kc = 0; kc < 8; kc++) qf[kc] = *(const bf16x8*)(qrow + kc * 32 + g * 8);

  float bk[4];
#pragma unroll
  for (int f = 0; f < 4; f++) bk[f] = __expf(-cl * (float)(f * 16 + c));

  f32x4 acc[16];
#pragma unroll
  for (int i = 0; i < 16; i++) acc[i] = (f32x4){0.f, 0.f, 0.f, 0.f};

  int tlo = s0 - WINDOW; if (tlo < 0) tlo = 0; tlo >>= 6;
  int ntiles = qt - tlo + 1;

  if (gid == 1) attn_stage(QKV, Vt, b, tlo * 64, smem, smem + 32768, tg);
  __syncthreads();
  for (int k = 0; k < ntiles; k++) {
    int bsel = k & 1;
    char* kb = smem + bsel * 65536;
    if ((k & 1) == gid) {
      attn_compute(kb, kb + 32768, (u16*)(smem + 131072) + wq * 16 * 72,
                   qf, acc, s0, (tlo + k) * 64, wq, g, c, cl, bk);
    } else if (tlo + k + 1 <= qt) {
      char* kb2 = smem + (bsel ^ 1) * 65536;
      attn_stage(QKV, Vt, b, (tlo + k + 1) * 64, kb2, kb2 + 32768, tg);
    }
    __syncthreads();
  }

  float* sO = (float*)smem;
  if (gid == 1) {
#pragma unroll
    for (int of = 0; of < 16; of++)
#pragma unroll
      for (int r = 0; r < 4; r++)
        sO[(wq * 16 + g * 4 + r) * 256 + of * 16 + c] = acc[of][r];
  }
  __syncthreads();
  if (gid == 0) {
    float* orow = out + (size_t)(b * S_LEN + s0 + wq * 16 + g * 4) * HSZ;
#pragma unroll
    for (int of = 0; of < 16; of++)
#pragma unroll
      for (int r = 0; r < 4; r++)
        orow[(size_t)r * HSZ + of * 16 + c] =
            acc[of][r] + sO[(wq * 16 + g * 4 + r) * 256 + of * 16 + c];
  }
}

extern "C" void kernel_launch(void* const* d_in, const int* in_sizes, int n_in,
                              void* d_out, int out_size, void* d_ws, size_t ws_size,
                              hipStream_t stream) {
  const float* X     = (const float*)d_in[0];
  const float* Wq    = (const float*)d_in[1];
  const float* Wk    = (const float*)d_in[2];
  const float* Wv    = (const float*)d_in[3];
  const float* decay = (const float*)d_in[4];
  float* out = (float*)d_out;

  char* ws = (char*)d_ws;
  u16* Xb  = (u16*)ws;                                   // 64 MiB
  u16* Wt  = (u16*)(ws + 67108864);                      // 3 MiB
  u16* QKV = (u16*)(ws + 67108864 + 3145728);            // 24 MiB
  u16* Vt  = (u16*)(ws + 67108864 + 3145728 + 25165824); // 8 MiB

  k_convertX  <<<16384, 256, 0, stream>>>(X, Xb);
  k_transposeW<<<1536,  256, 0, stream>>>(Wq, Wk, Wv, Wt);
  k_gemm      <<<512,   512, 0, stream>>>(Xb, Wt, QKV);
  k_transposeV<<<1024,  256, 0, stream>>>(QKV, Vt);
  k_attn      <<<256,   512, 0, stream>>>(QKV, Vt, decay, out);
}

// Round 17
// 108.569 us; speedup vs baseline: 1.1194x; 1.1194x over previous
//
#include <hip/hip_runtime.h>

// RetNet retention: B=4, S=4096, D=2048, H=256, gamma=1.05.
// R17 = R13 (best, 110.0us) + k_prep: convertX and transposeW merged into
// one dispatch (saves a launch + overlaps the 1536-block transpose with the
// convert tail). Gemm = R13's 256x192 BK=64 8-phase (4 gemm-schedule
// hypotheses refuted R14-16: prefetch depth, compiler pinning, occupancy,
// barrier frequency -- all neutral-or-worse; ~950 TF is this shape's
// structure limit). attn W=128 parity-split, XCD swizzle.

typedef unsigned short u16;
typedef __attribute__((ext_vector_type(8))) short bf16x8;
typedef __attribute__((ext_vector_type(4))) float f32x4;

#define S_LEN 4096
#define DMODEL 2048
#define HSZ 256
#define NQKV 768
#define WINDOW 128
#define NT 32

__device__ __forceinline__ u16 f2bf(float f) {
  union { float f; unsigned u; } v; v.f = f;
  unsigned r = v.u + 0x7FFFu + ((v.u >> 16) & 1u);   // RNE
  return (u16)(r >> 16);
}

__device__ __forceinline__ void glds16(const void* g, void* l) {
  __builtin_amdgcn_global_load_lds(
      (const __attribute__((address_space(1))) unsigned int*)g,
      (__attribute__((address_space(3))) unsigned int*)l, 16, 0, 0);
}

#define BAR() __builtin_amdgcn_s_barrier()
#define LGKM0() do { asm volatile("s_waitcnt lgkmcnt(0)" ::: "memory"); \
                     __builtin_amdgcn_sched_barrier(0); } while (0)
#define VM3() do { asm volatile("s_waitcnt vmcnt(3)" ::: "memory"); \
                   __builtin_amdgcn_sched_barrier(0); } while (0)
#define VM0() do { asm volatile("s_waitcnt vmcnt(0)" ::: "memory"); \
                   __builtin_amdgcn_sched_barrier(0); } while (0)

// ------------- 1) fused: X fp32->bf16 (blocks 0..16383) + W transpose ------
__global__ __launch_bounds__(256) void k_prep(const float* __restrict__ X,
                                              u16* __restrict__ Xb,
                                              const float* __restrict__ Wq,
                                              const float* __restrict__ Wk,
                                              const float* __restrict__ Wv,
                                              u16* __restrict__ Wt) {
  __shared__ float s[32][33];
  if (blockIdx.x < 16384) {
    int t = blockIdx.x * 256 + threadIdx.x;
    const float4* src = (const float4*)X;
    float4 a = src[t * 2], b = src[t * 2 + 1];
    uint4 o;
    o.x = f2bf(a.x) | ((unsigned)f2bf(a.y) << 16);
    o.y = f2bf(a.z) | ((unsigned)f2bf(a.w) << 16);
    o.z = f2bf(b.x) | ((unsigned)f2bf(b.y) << 16);
    o.w = f2bf(b.z) | ((unsigned)f2bf(b.w) << 16);
    ((uint4*)Xb)[t] = o;
    return;
  }
  int bid = blockIdx.x - 16384;
  int nt = bid % 24, kt = bid / 24;
  int n0 = nt * 32, k0 = kt * 32;
  const float* W = (n0 < 256) ? Wq : (n0 < 512 ? Wk : Wv);
  int nc = n0 & 255;
  int tx = threadIdx.x & 31, ty = threadIdx.x >> 5;
#pragma unroll
  for (int j = 0; j < 4; j++)
    s[ty + j * 8][tx] = W[(k0 + ty + j * 8) * HSZ + nc + tx];
  __syncthreads();
#pragma unroll
  for (int j = 0; j < 4; j++) {
    int nl = ty + j * 8;
    Wt[(n0 + nl) * DMODEL + k0 + tx] = f2bf(s[tx][nl]);
  }
}

// ---------------- 2) QKV GEMM: 256x192, BK=64, bf16 both operands ----------
__device__ __forceinline__ bf16x8 ldf(const char* hbase, int r, int ks) {
  return *(const bf16x8*)(hbase + r * 128 + ((ks ^ (r & 7)) << 4));
}
__device__ __forceinline__ void stageh(const u16* src, char* base, int w, int l) {
  int r0 = l >> 3, sl = (l & 7) ^ (l >> 3);
#pragma unroll
  for (int s = 0; s < 2; s++)
    glds16(src + (size_t)((s * 8 + w) * 8 + r0) * DMODEL + sl * 8,
           base + (s * 8 + w) * 1024);
}
__device__ __forceinline__ void stageB(const u16* Bsrc, char* bufbase, int t,
                                       int cb, int w, int l) {
  int r0 = l >> 3, sl = (l & 7) ^ r0;
  glds16(Bsrc + (size_t)(cb * 64 + w * 8 + r0) * DMODEL + t * 64 + sl * 8,
         bufbase + cb * 8192 + w * 1024);
}
__device__ __forceinline__ void read_a(const char* Ac, int c, int g, int fmoff,
                                       bf16x8 (&dst)[4][2]) {
#pragma unroll
  for (int m = 0; m < 4; m++) {
    int r = (m + fmoff) * 16 + c;
    dst[m][0] = ldf(Ac, r, g);
    dst[m][1] = ldf(Ac, r, 4 + g);
  }
}
__device__ __forceinline__ void read_b01(const char* Bc, int wn, int c, int g,
                                         bf16x8 (&dst)[2][2]) {
#pragma unroll
  for (int n = 0; n < 2; n++) {
    int r = wn * 48 + n * 16 + c;
    dst[n][0] = ldf(Bc, r, g);
    dst[n][1] = ldf(Bc, r, 4 + g);
  }
}
__device__ __forceinline__ void read_b2(const char* Bc, int wn, int c, int g,
                                        bf16x8 (&dst)[2]) {
  int r = wn * 48 + 32 + c;
  dst[0] = ldf(Bc, r, g);
  dst[1] = ldf(Bc, r, 4 + g);
}
__device__ __forceinline__ void mfma16(const bf16x8 (&A)[4][2], const bf16x8 (&Bf)[2][2],
                                       f32x4 (&acc)[8][3], int mo) {
  __builtin_amdgcn_s_setprio(1);
#pragma unroll
  for (int m = 0; m < 4; m++)
#pragma unroll
    for (int n = 0; n < 2; n++)
#pragma unroll
      for (int k = 0; k < 2; k++)
        acc[m + mo][n] = __builtin_amdgcn_mfma_f32_16x16x32_bf16(
            A[m][k], Bf[n][k], acc[m + mo][n], 0, 0, 0);
  __builtin_amdgcn_s_setprio(0);
}
__device__ __forceinline__ void mfma8(const bf16x8 (&A)[4][2], const bf16x8 (&Bf)[2],
                                      f32x4 (&acc)[8][3], int mo) {
  __builtin_amdgcn_s_setprio(1);
#pragma unroll
  for (int m = 0; m < 4; m++)
#pragma unroll
    for (int k = 0; k < 2; k++)
      acc[m + mo][2] = __builtin_amdgcn_mfma_f32_16x16x32_bf16(
          A[m][k], Bf[k], acc[m + mo][2], 0, 0, 0);
  __builtin_amdgcn_s_setprio(0);
}

__global__ __launch_bounds__(512, 1) void k_gemm(const u16* __restrict__ Xb,
                                                 const u16* __restrict__ Wt,
                                                 u16* __restrict__ QKV) {
  __shared__ __attribute__((aligned(16))) char lds[114688];  // A 2x32K + B 2x24K
  int tid = threadIdx.x;
  int w = tid >> 6, l = tid & 63, g = l >> 4, c = l & 15;
  int wm = w >> 2, wn = w & 3;          // 2 x 4 wave grid
  int swz = (blockIdx.x & 7) * 32 + (blockIdx.x >> 3);  // bijective (256%8==0)
  int bm = swz & 63, bn = swz >> 6;
  size_t m0 = (size_t)bm * 256, n0 = (size_t)bn * 192;
  const u16* Asrc = Xb + m0 * DMODEL;
  const u16* Bsrc = Wt + n0 * DMODEL;
#define ABASE(b, h) (lds + (b) * 32768 + (h) * 16384)
#define BBUF(b)     (lds + 65536 + (b) * 24576)
#define SA(t, h) (Asrc + (size_t)((h) * 128) * DMODEL + (t) * 64)

  f32x4 acc[8][3];
#pragma unroll
  for (int i = 0; i < 8; i++)
#pragma unroll
    for (int j = 0; j < 3; j++) acc[i][j] = (f32x4){0.f, 0.f, 0.f, 0.f};

  stageh(SA(0, 0), ABASE(0, 0), w, l);
  stageh(SA(0, 1), ABASE(0, 1), w, l);
  stageB(Bsrc, BBUF(0), 0, 0, w, l);
  stageB(Bsrc, BBUF(0), 0, 1, w, l);
  stageB(Bsrc, BBUF(0), 0, 2, w, l);
  stageB(Bsrc, BBUF(1), 1, 0, w, l);
  stageB(Bsrc, BBUF(1), 1, 1, w, l);
  stageB(Bsrc, BBUF(1), 1, 2, w, l);
  VM3();
  BAR();

  bf16x8 af[4][2], af2[4][2], bf01[2][2], bs[2];
  for (int u = 0; u < NT; u += 2) {
    bool pre2 = (u + 2 < NT), pre3 = (u + 3 < NT);
    const char* Bc0 = BBUF(0);
    const char* Bc1 = BBUF(1);
    // ---- P1: MFMA u fm0-3 x n01; stage A(u+1) h0 -> Ab1 ----
    read_a(ABASE(0, wm), c, g, 0, af);
    read_b01(Bc0, wn, c, g, bf01);
    stageh(SA(u + 1, 0), ABASE(1, 0), w, l);
    LGKM0();
    mfma16(af, bf01, acc, 0);
    // ---- P2: MFMA u fm0-3 x n2; stage A(u+1) h1 -> Ab1 ----
    read_b2(Bc0, wn, c, g, bs);
    stageh(SA(u + 1, 1), ABASE(1, 1), w, l);
    LGKM0();
    mfma8(af, bs, acc, 0);
    BAR();                                   // release Bb0 (B(u) LDS-dead)
    // ---- P3: MFMA u fm4-7 x n2; stage B(u+2) c0,c1 -> Bb0 ----
    read_a(ABASE(0, wm), c, g, 4, af2);
    if (pre2) { stageB(Bsrc, BBUF(0), u + 2, 0, w, l);
                stageB(Bsrc, BBUF(0), u + 2, 1, w, l); }
    LGKM0();
    mfma8(af2, bs, acc, 4);
    // ---- P4: MFMA u fm4-7 x n01; stage B(u+2) c2; gate A(u+1) ----
    if (pre2) stageB(Bsrc, BBUF(0), u + 2, 2, w, l);
    mfma16(af2, bf01, acc, 4);
    if (pre2) { VM3(); } else { VM0(); }     // drain A(u+1) (+B(u+1) leftovers)
    BAR();
    // ---- P5: MFMA u+1 fm0-3 x n01; stage A(u+2) h0 -> Ab0 ----
    read_a(ABASE(1, wm), c, g, 0, af);
    read_b01(Bc1, wn, c, g, bf01);
    if (pre2) stageh(SA(u + 2, 0), ABASE(0, 0), w, l);
    LGKM0();
    mfma16(af, bf01, acc, 0);
    // ---- P6: MFMA u+1 fm0-3 x n2; stage A(u+2) h1 -> Ab0 ----
    read_b2(Bc1, wn, c, g, bs);
    if (pre2) stageh(SA(u + 2, 1), ABASE(0, 1), w, l);
    LGKM0();
    mfma8(af, bs, acc, 0);
    BAR();                                   // release Bb1 (B(u+1) LDS-dead)
    // ---- P7: MFMA u+1 fm4-7 x n2; stage B(u+3) c0,c1 -> Bb1 ----
    read_a(ABASE(1, wm), c, g, 4, af2);
    if (pre3) { stageB(Bsrc, BBUF(1), u + 3, 0, w, l);
                stageB(Bsrc, BBUF(1), u + 3, 1, w, l); }
    LGKM0();
    mfma8(af2, bs, acc, 4);
    // ---- P8: MFMA u+1 fm4-7 x n01; stage B(u+3) c2; gate A(u+2)+B(u+2) ----
    if (pre3) stageB(Bsrc, BBUF(1), u + 3, 2, w, l);
    mfma16(af2, bf01, acc, 4);
    if (pre2) { if (pre3) { VM3(); } else { VM0(); } }
    BAR();
  }

#pragma unroll
  for (int fm = 0; fm < 8; fm++)
#pragma unroll
    for (int fn = 0; fn < 3; fn++)
#pragma unroll
      for (int r = 0; r < 4; r++) {
        size_t row = m0 + wm * 128 + fm * 16 + g * 4 + r;
        size_t col = n0 + wn * 48 + fn * 16 + c;
        QKV[row * NQKV + col] = f2bf(acc[fm][fn][r]);
      }
}

// ---------------- 3) Vt[b][h][s] = V[b][s][h] ------------------------------
__global__ __launch_bounds__(256) void k_transposeV(const u16* __restrict__ QKV,
                                                    u16* __restrict__ Vt) {
  __shared__ __attribute__((aligned(16))) u16 s[64 * 72];
  int bid = blockIdx.x;
  int ht = bid & 3, st = (bid >> 2) & 63, b = bid >> 8;
  int s0 = st * 64, h0 = ht * 64;
  int tid = threadIdx.x;
#pragma unroll
  for (int i = 0; i < 2; i++) {
    int gr = i * 256 + tid;
    int rs = gr >> 3, cg = gr & 7;
    uint4 v = *(const uint4*)(QKV + (size_t)(b * S_LEN + s0 + rs) * NQKV + 512 + h0 + cg * 8);
    *(uint4*)(s + rs * 72 + cg * 8) = v;
  }
  __syncthreads();
#pragma unroll
  for (int i = 0; i < 2; i++) {
    int gr = i * 256 + tid;
    int hr = gr >> 3, cg = gr & 7;
    u16 u[8];
#pragma unroll
    for (int j = 0; j < 8; j++) u[j] = s[(cg * 8 + j) * 72 + hr];
    uint4 o;
    o.x = u[0] | ((unsigned)u[1] << 16);
    o.y = u[2] | ((unsigned)u[3] << 16);
    o.z = u[4] | ((unsigned)u[5] << 16);
    o.w = u[6] | ((unsigned)u[7] << 16);
    *(uint4*)(Vt + (size_t)b * (HSZ * S_LEN) + (size_t)(h0 + hr) * S_LEN + s0 + cg * 8) = o;
  }
}

// ---------------- 4) banded retention, 8-wave parity split -----------------
__device__ __forceinline__ void attn_stage(const u16* __restrict__ QKV,
                                           const u16* __restrict__ Vt,
                                           int b, int t0, char* sK, char* sV, int tg) {
#pragma unroll
  for (int i = 0; i < 8; i++) {
    int gr = i * 256 + tg;
    {
      int row = gr >> 5, cg = gr & 31;
      uint4 v = *(const uint4*)(QKV + (size_t)(b * S_LEN + t0 + row) * NQKV + 256 + cg * 8);
      *(uint4*)(sK + ((row * 512 + cg * 16) ^ ((row & 7) << 4))) = v;
    }
    {
      int h = gr >> 3, cg = gr & 7;
      uint4 v = *(const uint4*)(Vt + (size_t)b * (HSZ * S_LEN) + (size_t)h * S_LEN + t0 + cg * 8);
      *(uint4*)(sV + ((h * 128 + cg * 16) ^ ((h & 7) << 4))) = v;
    }
  }
}

__device__ __forceinline__ void attn_compute(const char* sK, const char* sV,
                                             u16* sPw, const bf16x8 (&qf)[8],
                                             f32x4 (&acc)[16], int s0, int t0,
                                             int wq, int g, int c, float cl,
                                             const float (&bk)[4]) {
  f32x4 z = {0.f, 0.f, 0.f, 0.f};
  f32x4 sc[4];
  sc[0] = z; sc[1] = z; sc[2] = z; sc[3] = z;
#pragma unroll
  for (int f = 0; f < 4; f++) {
    int row = f * 16 + c;
    int rb = row * 512, sw = (row & 7) << 4;
#pragma unroll
    for (int kc = 0; kc < 8; kc++) {
      bf16x8 kf = *(const bf16x8*)(sK + ((rb + kc * 64 + g * 16) ^ sw));
      sc[f] = __builtin_amdgcn_mfma_f32_16x16x32_bf16(qf[kc], kf, sc[f], 0, 0, 0);
    }
  }
  int qb = s0 + wq * 16 + g * 4;
  int dt = qb - t0;
  float ar[4];
#pragma unroll
  for (int r = 0; r < 4; r++) ar[r] = __expf(cl * (float)(dt + r)) * 0.0625f;
#pragma unroll
  for (int f = 0; f < 4; f++) {
#pragma unroll
    for (int r = 0; r < 4; r++) {
      float p = sc[f][r] * ar[r] * bk[f];
      p = (dt + r - f * 16 - c >= 0) ? p : 0.f;
      sPw[(g * 4 + r) * 72 + f * 16 + c] = f2bf(p);
    }
  }
  bf16x8 pa[2];
#pragma unroll
  for (int kc = 0; kc < 2; kc++)
    pa[kc] = *(const bf16x8*)(sPw + c * 72 + kc * 32 + g * 8);
#pragma unroll
  for (int of = 0; of < 16; of++) {
#pragma unroll
    for (int kc = 0; kc < 2; kc++) {
      int hr = of * 16 + c;
      bf16x8 vf = *(const bf16x8*)(sV + ((hr * 128 + kc * 64 + g * 16) ^ ((hr & 7) << 4)));
      acc[of] = __builtin_amdgcn_mfma_f32_16x16x32_bf16(pa[kc], vf, acc[of], 0, 0, 0);
    }
  }
}

__global__ __launch_bounds__(512, 2) void k_attn(const u16* __restrict__ QKV,
                                                 const u16* __restrict__ Vt,
                                                 const float* __restrict__ decay,
                                                 float* __restrict__ out) {
  __shared__ __attribute__((aligned(16))) char smem[140288];
  int logical = (blockIdx.x & 7) * 32 + (blockIdx.x >> 3);
  int b = logical >> 6, qt = logical & 63, s0 = qt * 64;
  int tid = threadIdx.x, wid = tid >> 6, l = tid & 63, g = l >> 4, c = l & 15;
  int gid = wid >> 2, wq = wid & 3, tg = tid & 255;
  float cl = -decay[0];

  bf16x8 qf[8];
  const u16* qrow = QKV + (size_t)(b * S_LEN + s0 + wq * 16 + c) * NQKV;
#pragma unroll
  for (int kc = 0; kc < 8; kc++) qf[kc] = *(const bf16x8*)(qrow + kc * 32 + g * 8);

  float bk[4];
#pragma unroll
  for (int f = 0; f < 4; f++) bk[f] = __expf(-cl * (float)(f * 16 + c));

  f32x4 acc[16];
#pragma unroll
  for (int i = 0; i < 16; i++) acc[i] = (f32x4){0.f, 0.f, 0.f, 0.f};

  int tlo = s0 - WINDOW; if (tlo < 0) tlo = 0; tlo >>= 6;
  int ntiles = qt - tlo + 1;

  if (gid == 1) attn_stage(QKV, Vt, b, tlo * 64, smem, smem + 32768, tg);
  __syncthreads();
  for (int k = 0; k < ntiles; k++) {
    int bsel = k & 1;
    char* kb = smem + bsel * 65536;
    if ((k & 1) == gid) {
      attn_compute(kb, kb + 32768, (u16*)(smem + 131072) + wq * 16 * 72,
                   qf, acc, s0, (tlo + k) * 64, wq, g, c, cl, bk);
    } else if (tlo + k + 1 <= qt) {
      char* kb2 = smem + (bsel ^ 1) * 65536;
      attn_stage(QKV, Vt, b, (tlo + k + 1) * 64, kb2, kb2 + 32768, tg);
    }
    __syncthreads();
  }

  float* sO = (float*)smem;
  if (gid == 1) {
#pragma unroll
    for (int of = 0; of < 16; of++)
#pragma unroll
      for (int r = 0; r < 4; r++)
        sO[(wq * 16 + g * 4 + r) * 256 + of * 16 + c] = acc[of][r];
  }
  __syncthreads();
  if (gid == 0) {
    float* orow = out + (size_t)(b * S_LEN + s0 + wq * 16 + g * 4) * HSZ;
#pragma unroll
    for (int of = 0; of < 16; of++)
#pragma unroll
      for (int r = 0; r < 4; r++)
        orow[(size_t)r * HSZ + of * 16 + c] =
            acc[of][r] + sO[(wq * 16 + g * 4 + r) * 256 + of * 16 + c];
  }
}

extern "C" void kernel_launch(void* const* d_in, const int* in_sizes, int n_in,
                              void* d_out, int out_size, void* d_ws, size_t ws_size,
                              hipStream_t stream) {
  const float* X     = (const float*)d_in[0];
  const float* Wq    = (const float*)d_in[1];
  const float* Wk    = (const float*)d_in[2];
  const float* Wv    = (const float*)d_in[3];
  const float* decay = (const float*)d_in[4];
  float* out = (float*)d_out;

  char* ws = (char*)d_ws;
  u16* Xb  = (u16*)ws;                                   // 64 MiB
  u16* Wt  = (u16*)(ws + 67108864);                      // 3 MiB
  u16* QKV = (u16*)(ws + 67108864 + 3145728);            // 24 MiB
  u16* Vt  = (u16*)(ws + 67108864 + 3145728 + 25165824); // 8 MiB

  k_prep      <<<17920, 256, 0, stream>>>(X, Xb, Wq, Wk, Wv, Wt);
  k_gemm      <<<256,   512, 0, stream>>>(Xb, Wt, QKV);
  k_transposeV<<<1024,  256, 0, stream>>>(QKV, Vt);
  k_attn      <<<256,   512, 0, stream>>>(QKV, Vt, decay, out);
}